// Round 16
// baseline (129.952 us; speedup 1.0000x reference)
//
#include <hip/hip_runtime.h>
#include <stdint.h>

#pragma clang fp contract(off)

#define NBOX 8000      // 5x40x40 + 5x80x80
#define NFAST 896      // fast path cap: W<=14, tri mask = 6720 u64 = 52.5 KB
#define NB 16          // grid blocks (<< 256 CUs -> co-resident)
typedef unsigned long long u64;

// Magic-tagged control words: ws is 0xAA-poisoned (or zeroed) before launch;
// (v & 0xFFFF0000) can never equal 0x7E30/0x7E32 from poison -> NO INIT NEEDED.
#define CNT_TAG 0x7E300000   // decode block b posts CNT_TAG | count
#define ARR_TAG 0x7E320000   // block b posts ARR_TAG | phase (2=rank done, 3=mask done)

__device__ __forceinline__ u64 aload64(u64* p) {
    return __hip_atomic_load(p, __ATOMIC_RELAXED, __HIP_MEMORY_SCOPE_AGENT);
}
__device__ __forceinline__ void astore64(u64* p, u64 v) {
    __hip_atomic_store(p, v, __ATOMIC_RELAXED, __HIP_MEMORY_SCOPE_AGENT);
}
__device__ __forceinline__ int aloadi(int* p) {
    return __hip_atomic_load(p, __ATOMIC_RELAXED, __HIP_MEMORY_SCOPE_AGENT);
}
__device__ __forceinline__ void astorei(int* p, int v) {
    __hip_atomic_store(p, v, __ATOMIC_RELAXED, __HIP_MEMORY_SCOPE_AGENT);
}

// pack 4 non-negative u16 coords: x1 | y1<<16 | x2<<32 | y2<<48
__device__ __forceinline__ u64 packBox(int x1, int y1, int x2, int y2) {
    return (u64)(unsigned)(x1 | (y1 << 16)) | ((u64)(unsigned)(x2 | (y2 << 16)) << 32);
}
__device__ __forceinline__ void unpackBox(u64 v, int& x1, int& y1, int& x2, int& y2) {
    unsigned lo = (unsigned)v, hi = (unsigned)(v >> 32);
    x1 = (int)(lo & 0xffffu); y1 = (int)(lo >> 16);
    x2 = (int)(hi & 0xffffu); y2 = (int)(hi >> 16);
}
__device__ __forceinline__ u64 iouBit(u64 rp, int ra, int cx1, int cy1, int cx2, int cy2,
                                      int car, bool cv) {
    int rx1, ry1, rx2, ry2; unpackBox(rp, rx1, ry1, rx2, ry2);
    int iw = max(min(rx2, cx2) - max(rx1, cx1), 0);
    int ih = max(min(ry2, cy2) - max(ry1, cy1), 0);
    int I = __mul24(iw, ih); int P = ra + car;          // exact: ints < 2^23
    return __ballot(cv && (I < P) && (3 * I > P));      // uni>0 && inter>0.5*uni
}

// ctrl (int*): cnt_b at ctrl[b*32] (b<8); arr_b at ctrl[(16+b)*32]. 128-B spacing.
__global__ __launch_bounds__(1024) void k_all(
    const float* __restrict__ outs0, const float* __restrict__ outs1,
    float* __restrict__ out,
    int* __restrict__ ctrl,
    u64* __restrict__ gKey, u64* __restrict__ gBox,      // [8192] per-block segments
    u64* __restrict__ sKey, u64* __restrict__ sBox,      // [1024] sorted
    u64* __restrict__ triG,                              // [6720] tri mask
    u64* __restrict__ fbKey, u64* __restrict__ fbBoxC,   // fallback scratch
    u64* __restrict__ sKey2, u64* __restrict__ sBox2, u64* __restrict__ kArr)
{
    __shared__ __attribute__((aligned(16))) char pool[53760];  // tri overlay (52.5 KB)
    u64* lkey = (u64*)pool;            // packed keys   [<=1024]
    u64* lbox = (u64*)(pool + 8192);   // packed boxes  [<=1024]
    u64* tri  = (u64*)pool;            // block 0 scan overlay
    __shared__ int cnt64[64];
    __shared__ int pre[8], cnts[8];
    __shared__ int sCnt, sN;
    __shared__ u64 keptW[16];
    const int tid = threadIdx.x, bid = blockIdx.x;
    const int wv = tid >> 6, lane = tid & 63;
    int* cntw = ctrl;
    int* arrw = ctrl + 16 * 32;

    if (tid == 0) sCnt = 0;
    __syncthreads();

    // ---- Phase A: decode blocks 0..7, one box/thread, publish to own segment ----
    bool valid = false; u64 myKey = 0, myPk = 0;
    if (bid < 8) {
        int g = (bid << 10) + tid;
        if (g < NBOX) {
            const float* src; int local, i, j; float xps, yps; int pp;
            if (g < 1600) { src = outs0; local = g;        i = local/40; j = local - i*40; xps=16.f; yps=12.f; pp=1600; }
            else          { src = outs1; local = g - 1600; i = local/80; j = local - i*80; xps= 8.f; yps= 6.f; pp=6400; }
            float prob = src[local];
            if (prob > 0.9f) {
                float b1 = src[pp + local], b2 = src[2*pp + local];
                float b3 = src[3*pp + local], b4 = src[4*pp + local];
                // reference: ROW idx i scales x (ii[:,None]); COL idx j scales y
                float c1 = b1*xps + (float)i*xps;
                float c2 = b2*yps + (float)j*yps;
                float X1 = rintf(c1), Y1 = rintf(c2);
                float X2 = rintf(b3*640.0f + c1), Y2 = rintf(b4*480.0f + c2);
                unsigned u = __float_as_uint(prob);
                u ^= (u & 0x80000000u) ? 0xFFFFFFFFu : 0x80000000u;  // monotone map
                myKey = ((u64)(~u) << 32) | (unsigned)g;  // asc = desc score, asc g
                myPk = packBox((int)X1, (int)Y1, (int)X2, (int)Y2);
                valid = true;
            }
        }
        u64 bal = __ballot(valid);
        int wcnt = (int)__popcll(bal);
        int wbase = 0;
        if (lane == 0 && wcnt) wbase = atomicAdd(&sCnt, wcnt);
        wbase = __shfl(wbase, 0);
        int posl = wbase + (int)__popcll(bal & ((1ULL << lane) - 1ULL));
        if (valid) {
            astore64(&gKey[(bid << 10) + posl], myKey);
            astore64(&gBox[(bid << 10) + posl], myPk);
        }
        __syncthreads();   // drain segment stores (vmcnt(0) at barrier)
        if (tid == 0) astorei(&cntw[bid * 32], CNT_TAG | sCnt);
    }

    // ---- all blocks: poll the 8 count markers, compute n + prefix locally ----
    if (wv == 0) {
        bool need = lane < 8;
        int v = 0;
        for (;;) {
            if (need) v = aloadi(&cntw[lane * 32]);
            bool ok = !need || ((v & 0xFFFF0000) == CNT_TAG);
            if (__ballot(!ok) == 0) break;
            __builtin_amdgcn_s_sleep(1);
        }
        if (need) {
            int c = v & 0xFFFF;
            int p2 = 0;
            #pragma unroll
            for (int i2 = 0; i2 < 8; ++i2) {
                int ci = __shfl(c, i2);
                if (i2 < lane) p2 += ci;
            }
            pre[lane] = p2;
            cnts[lane] = c;
            if (lane == 7) sN = p2 + c;
        }
    }
    __syncthreads();
    int n = sN; if (n > NBOX) n = NBOX;

    if (n <= NFAST) {
        const int W = (n + 63) >> 6;
        // ---- zero partition, 128-B aligned split ----
        int zb = (5 * n + 31) & ~31;
        if (bid == 0) {
            for (int t = tid; t < zb; t += 1024) out[t] = 0.f;
        } else {
            for (int t = zb + ((bid - 1) << 10) + tid; t < 5 * NBOX; t += 15 * 1024)
                out[t] = 0.f;
        }

        // ---- bulk-load 8 segments -> packed LDS ----
        #pragma unroll
        for (int b2 = 0; b2 < 8; ++b2) {
            int c = cnts[b2], p0 = pre[b2];
            for (int i2 = tid; i2 < c; i2 += 1024) {
                lkey[p0 + i2] = aload64(&gKey[(b2 << 10) + i2]);
                lbox[p0 + i2] = aload64(&gBox[(b2 << 10) + i2]);
            }
        }
        if (tid < 64) cnt64[tid] = 0;
        __syncthreads();

        // ---- rank-count own p-slice over packed LDS keys ----
        int pc = (n + 15) >> 4;
        int pl = tid >> 4, qs = tid & 15;
        int p = bid * pc + pl;
        bool pv = (pl < pc) && (p < n);
        if (pv) {
            u64 kp = lkey[p];
            int qlo = qs * pc, qhi = min(qlo + pc, n);
            int c2 = 0;
            for (int q = qlo; q < qhi; ++q) c2 += (lkey[q] < kp) ? 1 : 0;
            if (c2) atomicAdd(&cnt64[pl], c2);
        }
        __syncthreads();
        if (pv && qs == 0) {
            int rank = cnt64[pl];        // keys unique -> exact rank
            astore64(&sKey[rank], lkey[p]);
            astore64(&sBox[rank], lbox[p]);
        }
        __syncthreads();   // drain scatter
        if (tid == 0) astorei(&arrw[bid * 32], ARR_TAG | 2);
        // ---- poll: all 16 blocks at phase >= 2 ----
        if (wv == 0) {
            bool need = lane < 16;
            for (;;) {
                int v = 0;
                if (need) v = aloadi(&arrw[lane * 32]);
                bool ok = !need || (((v & 0xFFFF0000) == ARR_TAG) && ((v & 0xFFFF) >= 2));
                if (__ballot(!ok) == 0) break;
                __builtin_amdgcn_s_sleep(1);
            }
        }
        __syncthreads();

        // ---- mask phase: sorted boxes -> LDS (reuse lkey region) ----
        u64* sb = lkey;
        for (int t = tid; t < n; t += 1024) sb[t] = aload64(&sBox[t]);
        __syncthreads();
        u64 myBoxS = 0;
        if (bid == 0 && tid < n) myBoxS = sb[tid];   // snapshot before tri overlay
        {
            int nq = (n + 3) >> 2;
            for (int rq = bid * 16 + wv; rq < nq; rq += NB * 16) {
                int r0 = rq << 2;
                int a = r0 >> 6;
                int rowBase = 64 * (a * W - (a * (a - 1)) / 2);
                int Wa = W - a;
                int rr1 = min(r0+1, n-1), rr2 = min(r0+2, n-1), rr3 = min(r0+3, n-1);
                u64 rp0 = sb[r0], rp1 = sb[rr1], rp2 = sb[rr2], rp3 = sb[rr3];
                int t1,t2,t3,t4;
                unpackBox(rp0,t1,t2,t3,t4); int ra0 = __mul24(t3-t1, t4-t2);
                unpackBox(rp1,t1,t2,t3,t4); int ra1 = __mul24(t3-t1, t4-t2);
                unpackBox(rp2,t1,t2,t3,t4); int ra2 = __mul24(t3-t1, t4-t2);
                unpackBox(rp3,t1,t2,t3,t4); int ra3 = __mul24(t3-t1, t4-t2);
                for (int k = 0; k < Wa; ++k) {
                    int wcol = a + k;
                    int c = (wcol << 6) + lane;
                    bool cv = c < n;
                    u64 cb = sb[cv ? c : (n - 1)];
                    int cx1, cy1, cx2, cy2; unpackBox(cb, cx1, cy1, cx2, cy2);
                    int car = __mul24(cx2 - cx1, cy2 - cy1);
                    u64 wb0 = iouBit(rp0, ra0, cx1, cy1, cx2, cy2, car, cv);
                    u64 wb1 = iouBit(rp1, ra1, cx1, cy1, cx2, cy2, car, cv);
                    u64 wb2 = iouBit(rp2, ra2, cx1, cy1, cx2, cy2, car, cv);
                    u64 wb3 = iouBit(rp3, ra3, cx1, cy1, cx2, cy2, car, cv);
                    if (lane < 4) {
                        int r = r0 + lane;
                        if (r < n) {
                            u64 word = (lane == 0) ? wb0 : (lane == 1) ? wb1
                                     : (lane == 2) ? wb2 : wb3;
                            int b = r & 63;
                            if (wcol == a) {   // diagonal word: clear cols <= r
                                u64 low = (b == 63) ? ~0ULL : ((1ULL << (b + 1)) - 1);
                                word &= ~low;
                            }
                            astore64(&triG[rowBase + b * Wa + k], word);
                        }
                    }
                }
            }
        }
        __syncthreads();   // drain tri stores

        if (bid != 0) {
            if (tid == 0) astorei(&arrw[bid * 32], ARR_TAG | 3);
            return;
        }
        // ---- block 0: poll blocks 1..15 at phase >= 3, tri -> LDS, scan, write ----
        if (wv == 0) {
            bool need = (lane >= 1) && (lane < 16);
            for (;;) {
                int v = 0;
                if (need) v = aloadi(&arrw[lane * 32]);
                bool ok = !need || (((v & 0xFFFF0000) == ARR_TAG) && ((v & 0xFFFF) >= 3));
                if (__ballot(!ok) == 0) break;
                __builtin_amdgcn_s_sleep(1);
            }
        }
        __syncthreads();
        {
            int A = n >> 6, B = n & 63;
            int total = 64 * (A * W - (A * (A - 1)) / 2) + B * (W - A);
            for (int t = tid; t < total; t += 1024) tri[t] = aload64(&triG[t]);
        }
        if (tid < 16) keptW[tid] = 0;
        __syncthreads();

        // ---- scan: in-word readlane greedy + LAZY advance-time suppression ----
        // (no fut register, no per-kept pops/loads; suppression computed once
        //  per word-advance from the keptW bitmask words, lane-parallel)
        if (tid < 64 && n > 0) {
            unsigned curLo, curHi;
            {
                u64 c0 = (n >= 64) ? ~0ULL : ((1ULL << n) - 1);
                curLo = (unsigned)__builtin_amdgcn_readfirstlane((int)(unsigned)c0);
                curHi = (unsigned)__builtin_amdgcn_readfirstlane((int)(unsigned)(c0 >> 32));
            }
            int cw = 0;
            for (;;) {
                int Wa = W - cw;
                int base = 64 * (cw * W - (cw * (cw - 1)) / 2);
                // preload diag word of row (64*cw + lane)
                unsigned rdLo = 0, rdHi = 0;
                {
                    int r = (cw << 6) + lane;
                    if (r < n) {
                        u64 v = tri[base + lane * Wa];
                        rdLo = (unsigned)v; rdHi = (unsigned)(v >> 32);
                    }
                }
                // serial in-word greedy (scalar ctz + readlane) -- R15-proven
                unsigned khLo = 0, khHi = 0;
                while (curLo | curHi) {
                    int b = curLo ? __builtin_ctz(curLo) : (32 + __builtin_ctz(curHi));
                    unsigned wLo = (unsigned)__builtin_amdgcn_readlane((int)rdLo, b);
                    unsigned wHi = (unsigned)__builtin_amdgcn_readlane((int)rdHi, b);
                    if (curLo) { khLo |= curLo & (0u - curLo); curLo &= curLo - 1; }
                    else       { khHi |= curHi & (0u - curHi); curHi &= curHi - 1; }
                    curLo &= ~wLo; curHi &= ~wHi;
                }
                if (lane == 0) keptW[cw] = ((u64)khHi << 32) | khLo;
                // lazy advance: find next word with surviving candidates
                int nw = cw + 1;
                bool adv = false;
                while (nw < W) {
                    // lane j ORs tri(row=64*wp+j, col word nw) over kept rows
                    unsigned sLo = 0, sHi = 0;
                    for (int wp = 0; wp <= cw; ++wp) {
                        u64 kwv = keptW[wp];          // uniform addr -> broadcast
                        if ((kwv >> lane) & 1ULL) {   // this lane's row was kept
                            int off = 64 * (wp * W - (wp * (wp - 1)) / 2)
                                    + lane * (W - wp) + (nw - wp);
                            u64 v = tri[off];
                            sLo |= (unsigned)v; sHi |= (unsigned)(v >> 32);
                        }
                    }
                    #pragma unroll
                    for (int m2 = 32; m2 >= 1; m2 >>= 1) {
                        sLo |= (unsigned)__shfl_xor((int)sLo, m2);
                        sHi |= (unsigned)__shfl_xor((int)sHi, m2);
                    }
                    int cnt2 = n - (nw << 6);
                    u64 wmask = (cnt2 >= 64) ? ~0ULL
                              : ((cnt2 > 0) ? ((1ULL << cnt2) - 1) : 0ULL);
                    u64 cand = wmask & ~(((u64)sHi << 32) | sLo);
                    if (cand) {
                        curLo = (unsigned)__builtin_amdgcn_readfirstlane((int)(unsigned)cand);
                        curHi = (unsigned)__builtin_amdgcn_readfirstlane((int)(unsigned)(cand >> 32));
                        cw = nw;
                        adv = true;
                        break;
                    }
                    nw++;
                }
                if (!adv) break;
            }
        }
        __syncthreads();

        if (tid < n && ((keptW[tid >> 6] >> (tid & 63)) & 1ULL)) {
            u64 key = aload64(&sKey[tid]);
            unsigned u = ~(unsigned)(key >> 32);
            float score = __uint_as_float(u ^ 0x80000000u);
            int x1, y1, x2, y2; unpackBox(myBoxS, x1, y1, x2, y2);
            out[5*tid+0] = score;
            out[5*tid+1] = (float)x1;
            out[5*tid+2] = (float)y1;
            out[5*tid+3] = (float)(x2 - x1);
            out[5*tid+4] = (float)(y2 - y1);
        }
    } else {
        // ===== correctness-only fallback (n > NFAST; never expected) =====
        int zb = (5 * n + 31) & ~31; if (zb > 5 * NBOX) zb = 5 * NBOX;
        if (bid != 0) {   // zero tail share and exit; block 0 is self-sufficient
            for (int t = zb + ((bid - 1) << 10) + tid; t < 5 * NBOX; t += 15 * 1024)
                out[t] = 0.f;
            return;
        }
        for (int t = tid; t < zb; t += 1024) out[t] = 0.f;
        if (tid == 0) sCnt = 0;
        __syncthreads();
        #pragma unroll
        for (int kk = 0; kk < 8; ++kk) {
            int g = (kk << 10) + tid;
            if (g < NBOX) {
                const float* src; int local, i, j; float xps, yps; int pp;
                if (g < 1600) { src = outs0; local = g;        i = local/40; j = local - i*40; xps=16.f; yps=12.f; pp=1600; }
                else          { src = outs1; local = g - 1600; i = local/80; j = local - i*80; xps= 8.f; yps= 6.f; pp=6400; }
                float prob = src[local];
                if (prob > 0.9f) {
                    float b1 = src[pp + local], b2 = src[2*pp + local];
                    float b3 = src[3*pp + local], b4 = src[4*pp + local];
                    float c1 = b1*xps + (float)i*xps;
                    float c2 = b2*yps + (float)j*yps;
                    float X1 = rintf(c1), Y1 = rintf(c2);
                    float X2 = rintf(b3*640.0f + c1), Y2 = rintf(b4*480.0f + c2);
                    unsigned u = __float_as_uint(prob);
                    u ^= (u & 0x80000000u) ? 0xFFFFFFFFu : 0x80000000u;
                    u64 key = ((u64)(~u) << 32) | (unsigned)g;
                    int pos = atomicAdd(&sCnt, 1);
                    if (pos < 8192) {
                        fbKey[pos]  = key;
                        fbBoxC[pos] = packBox((int)X1, (int)Y1, (int)X2, (int)Y2);
                    }
                }
            }
        }
        __syncthreads();
        for (int p = tid; p < n; p += 1024) {
            u64 kp = fbKey[p];
            int rank = 0;
            for (int q = 0; q < n; ++q) rank += (fbKey[q] < kp) ? 1 : 0;
            sKey2[rank] = kp;
            sBox2[rank] = fbBoxC[p];
        }
        __syncthreads();
        if (tid < 64) {
            int kc = 0;
            for (int base2 = 0; base2 < n; base2 += 64) {
                int p = base2 + lane;
                bool in = p < n;
                u64 bp = in ? sBox2[p] : 0, kp2 = in ? sKey2[p] : 0;
                int x1, y1, x2, y2; unpackBox(bp, x1, y1, x2, y2);
                int ar = __mul24(x2 - x1, y2 - y1);
                bool dead = !in;
                for (int k = 0; k < kc; ++k) {
                    int kx1, ky1, kx2, ky2; unpackBox(kArr[k], kx1, ky1, kx2, ky2);
                    int kar = __mul24(kx2 - kx1, ky2 - ky1);
                    int iw = max(min(x2, kx2) - max(x1, kx1), 0);
                    int ih = max(min(y2, ky2) - max(y1, ky1), 0);
                    int I = __mul24(iw, ih); int P = ar + kar;
                    if (I < P && 3 * I > P) dead = true;
                }
                u64 scan = __ballot(!dead);
                while (scan) {
                    int t = (int)__builtin_ctzll(scan);
                    scan &= scan - 1;
                    u64 tb = __shfl(bp, t);
                    if (lane == t) {
                        kArr[kc] = bp;
                        unsigned u = ~(unsigned)(kp2 >> 32);
                        float score = __uint_as_float(u ^ 0x80000000u);
                        out[5*p+0] = score;
                        out[5*p+1] = (float)x1; out[5*p+2] = (float)y1;
                        out[5*p+3] = (float)(x2 - x1); out[5*p+4] = (float)(y2 - y1);
                    }
                    kc++;
                    bool kill = false;
                    if (!dead && lane > t) {
                        int tx1, ty1, tx2, ty2; unpackBox(tb, tx1, ty1, tx2, ty2);
                        int tar = __mul24(tx2 - tx1, ty2 - ty1);
                        int iw = max(min(x2, tx2) - max(x1, tx1), 0);
                        int ih = max(min(y2, ty2) - max(y1, ty1), 0);
                        int I = __mul24(iw, ih); int P = ar + tar;
                        kill = (I < P) && (3 * I > P);
                    }
                    dead = dead || kill;
                    scan &= ~__ballot(dead);
                }
            }
        }
    }
}

extern "C" void kernel_launch(void* const* d_in, const int* in_sizes, int n_in,
                              void* d_out, int out_size, void* d_ws, size_t ws_size,
                              hipStream_t stream) {
    const float* outs0 = (const float*)d_in[0];
    const float* outs1 = (const float*)d_in[1];
    float* out = (float*)d_out;
    char* ws = (char*)d_ws;
    size_t o = 0;
    int* ctrl   = (int*)(ws + o); o += 4096;               // 32 words x 128 B spacing
    u64* gKey   = (u64*)(ws + o); o += (size_t)8192 * 8;   // 64 KB (per-block segments)
    u64* gBox   = (u64*)(ws + o); o += (size_t)8192 * 8;   // 64 KB
    u64* sKey   = (u64*)(ws + o); o += (size_t)1024 * 8;   // 8 KB
    u64* sBox   = (u64*)(ws + o); o += (size_t)1024 * 8;   // 8 KB
    u64* triG   = (u64*)(ws + o); o += (size_t)6720 * 8;   // 52.5 KB
    u64* fbKey  = (u64*)(ws + o); o += (size_t)8192 * 8;   // 64 KB (fallback)
    u64* fbBoxC = (u64*)(ws + o); o += (size_t)8192 * 8;   // 64 KB (fallback)
    u64* sKey2  = (u64*)(ws + o); o += (size_t)8192 * 8;   // 64 KB (fallback)
    u64* sBox2  = (u64*)(ws + o); o += (size_t)8192 * 8;   // 64 KB (fallback)
    u64* kArr   = (u64*)(ws + o); o += (size_t)8192 * 8;   // 64 KB (fallback)

    hipLaunchKernelGGL(k_all, dim3(NB), dim3(1024), 0, stream,
                       outs0, outs1, out, ctrl, gKey, gBox, sKey, sBox, triG,
                       fbKey, fbBoxC, sKey2, sBox2, kArr);
}

// Round 17
// 99.182 us; speedup vs baseline: 1.3102x; 1.3102x over previous
//
#include <hip/hip_runtime.h>
#include <stdint.h>

#pragma clang fp contract(off)

#define NBOX 8000      // 5x40x40 + 5x80x80
#define NFAST 896      // fast path cap: W<=14, tri mask = 6720 u64 = 52.5 KB
#define NB 16          // grid blocks (<< 256 CUs -> co-resident)
typedef unsigned long long u64;

// Magic-tagged control words: ws is 0xAA-poisoned (or zeroed) before launch;
// (v & 0xFFFF0000) can never equal 0x7E30/0x7E32 from poison -> NO INIT NEEDED.
#define CNT_TAG 0x7E300000   // decode block b posts CNT_TAG | count
#define ARR_TAG 0x7E320000   // block b posts ARR_TAG | phase (2=rank done, 3=mask done)

__device__ __forceinline__ u64 aload64(u64* p) {
    return __hip_atomic_load(p, __ATOMIC_RELAXED, __HIP_MEMORY_SCOPE_AGENT);
}
__device__ __forceinline__ void astore64(u64* p, u64 v) {
    __hip_atomic_store(p, v, __ATOMIC_RELAXED, __HIP_MEMORY_SCOPE_AGENT);
}
__device__ __forceinline__ int aloadi(int* p) {
    return __hip_atomic_load(p, __ATOMIC_RELAXED, __HIP_MEMORY_SCOPE_AGENT);
}
__device__ __forceinline__ void astorei(int* p, int v) {
    __hip_atomic_store(p, v, __ATOMIC_RELAXED, __HIP_MEMORY_SCOPE_AGENT);
}
__device__ __forceinline__ u64 shflxor64(u64 v, int m) {
    int lo = __shfl_xor((int)(unsigned)v, m);
    int hi = __shfl_xor((int)(unsigned)(v >> 32), m);
    return ((u64)(unsigned)hi << 32) | (unsigned)lo;
}

// pack 4 non-negative u16 coords: x1 | y1<<16 | x2<<32 | y2<<48
__device__ __forceinline__ u64 packBox(int x1, int y1, int x2, int y2) {
    return (u64)(unsigned)(x1 | (y1 << 16)) | ((u64)(unsigned)(x2 | (y2 << 16)) << 32);
}
__device__ __forceinline__ void unpackBox(u64 v, int& x1, int& y1, int& x2, int& y2) {
    unsigned lo = (unsigned)v, hi = (unsigned)(v >> 32);
    x1 = (int)(lo & 0xffffu); y1 = (int)(lo >> 16);
    x2 = (int)(hi & 0xffffu); y2 = (int)(hi >> 16);
}
__device__ __forceinline__ u64 iouBit(u64 rp, int ra, int cx1, int cy1, int cx2, int cy2,
                                      int car, bool cv) {
    int rx1, ry1, rx2, ry2; unpackBox(rp, rx1, ry1, rx2, ry2);
    int iw = max(min(rx2, cx2) - max(rx1, cx1), 0);
    int ih = max(min(ry2, cy2) - max(ry1, cy1), 0);
    int I = __mul24(iw, ih); int P = ra + car;          // exact: ints < 2^23
    return __ballot(cv && (I < P) && (3 * I > P));      // uni>0 && inter>0.5*uni
}

// ctrl (int*): cnt_b at ctrl[b*32] (b<8); arr_b at ctrl[(16+b)*32]. 128-B spacing.
__global__ __launch_bounds__(1024) void k_all(
    const float* __restrict__ outs0, const float* __restrict__ outs1,
    float* __restrict__ out,
    int* __restrict__ ctrl,
    u64* __restrict__ gKey, u64* __restrict__ gBox,      // [8192] per-block segments
    u64* __restrict__ sKey, u64* __restrict__ sBox,      // [1024] sorted
    u64* __restrict__ triG,                              // [6720] tri mask
    u64* __restrict__ fbKey, u64* __restrict__ fbBoxC,   // fallback scratch
    u64* __restrict__ sKey2, u64* __restrict__ sBox2, u64* __restrict__ kArr)
{
    __shared__ __attribute__((aligned(16))) char pool[53760];  // tri overlay (52.5 KB)
    u64* lkey = (u64*)pool;            // packed keys   [<=1024]
    u64* lbox = (u64*)(pool + 8192);   // packed boxes  [<=1024]
    u64* tri  = (u64*)pool;            // block 0 scan overlay
    __shared__ int cnt64[64];
    __shared__ int pre[8], cnts[8];
    __shared__ int sCnt, sN;
    __shared__ u64 keptW[16];
    const int tid = threadIdx.x, bid = blockIdx.x;
    const int wv = tid >> 6, lane = tid & 63;
    int* cntw = ctrl;
    int* arrw = ctrl + 16 * 32;

    if (tid == 0) sCnt = 0;
    __syncthreads();

    // ---- Phase A: decode blocks 0..7, one box/thread, publish to own segment ----
    bool valid = false; u64 myKey = 0, myPk = 0;
    if (bid < 8) {
        int g = (bid << 10) + tid;
        if (g < NBOX) {
            const float* src; int local, i, j; float xps, yps; int pp;
            if (g < 1600) { src = outs0; local = g;        i = local/40; j = local - i*40; xps=16.f; yps=12.f; pp=1600; }
            else          { src = outs1; local = g - 1600; i = local/80; j = local - i*80; xps= 8.f; yps= 6.f; pp=6400; }
            float prob = src[local];
            if (prob > 0.9f) {
                float b1 = src[pp + local], b2 = src[2*pp + local];
                float b3 = src[3*pp + local], b4 = src[4*pp + local];
                // reference: ROW idx i scales x (ii[:,None]); COL idx j scales y
                float c1 = b1*xps + (float)i*xps;
                float c2 = b2*yps + (float)j*yps;
                float X1 = rintf(c1), Y1 = rintf(c2);
                float X2 = rintf(b3*640.0f + c1), Y2 = rintf(b4*480.0f + c2);
                unsigned u = __float_as_uint(prob);
                u ^= (u & 0x80000000u) ? 0xFFFFFFFFu : 0x80000000u;  // monotone map
                myKey = ((u64)(~u) << 32) | (unsigned)g;  // asc = desc score, asc g
                myPk = packBox((int)X1, (int)Y1, (int)X2, (int)Y2);
                valid = true;
            }
        }
        u64 bal = __ballot(valid);
        int wcnt = (int)__popcll(bal);
        int wbase = 0;
        if (lane == 0 && wcnt) wbase = atomicAdd(&sCnt, wcnt);
        wbase = __shfl(wbase, 0);
        int posl = wbase + (int)__popcll(bal & ((1ULL << lane) - 1ULL));
        if (valid) {
            astore64(&gKey[(bid << 10) + posl], myKey);
            astore64(&gBox[(bid << 10) + posl], myPk);
        }
        __syncthreads();   // drain segment stores (vmcnt(0) at barrier)
        if (tid == 0) astorei(&cntw[bid * 32], CNT_TAG | sCnt);
    }

    // ---- all blocks: poll the 8 count markers, compute n + prefix locally ----
    if (wv == 0) {
        bool need = lane < 8;
        int v = 0;
        for (;;) {
            if (need) v = aloadi(&cntw[lane * 32]);
            bool ok = !need || ((v & 0xFFFF0000) == CNT_TAG);
            if (__ballot(!ok) == 0) break;
            __builtin_amdgcn_s_sleep(1);
        }
        if (need) {
            int c = v & 0xFFFF;
            int p2 = 0;
            #pragma unroll
            for (int i2 = 0; i2 < 8; ++i2) {
                int ci = __shfl(c, i2);
                if (i2 < lane) p2 += ci;
            }
            pre[lane] = p2;
            cnts[lane] = c;
            if (lane == 7) sN = p2 + c;
        }
    }
    __syncthreads();
    int n = sN; if (n > NBOX) n = NBOX;

    if (n <= NFAST) {
        const int W = (n + 63) >> 6;
        // ---- zero partition, 128-B aligned split ----
        int zb = (5 * n + 31) & ~31;
        if (bid == 0) {
            for (int t = tid; t < zb; t += 1024) out[t] = 0.f;
        } else {
            for (int t = zb + ((bid - 1) << 10) + tid; t < 5 * NBOX; t += 15 * 1024)
                out[t] = 0.f;
        }

        // ---- bulk-load 8 segments -> packed LDS ----
        #pragma unroll
        for (int b2 = 0; b2 < 8; ++b2) {
            int c = cnts[b2], p0 = pre[b2];
            for (int i2 = tid; i2 < c; i2 += 1024) {
                lkey[p0 + i2] = aload64(&gKey[(b2 << 10) + i2]);
                lbox[p0 + i2] = aload64(&gBox[(b2 << 10) + i2]);
            }
        }
        if (tid < 64) cnt64[tid] = 0;
        __syncthreads();

        // ---- rank-count own p-slice over packed LDS keys ----
        int pc = (n + 15) >> 4;
        int pl = tid >> 4, qs = tid & 15;
        int p = bid * pc + pl;
        bool pv = (pl < pc) && (p < n);
        if (pv) {
            u64 kp = lkey[p];
            int qlo = qs * pc, qhi = min(qlo + pc, n);
            int c2 = 0;
            for (int q = qlo; q < qhi; ++q) c2 += (lkey[q] < kp) ? 1 : 0;
            if (c2) atomicAdd(&cnt64[pl], c2);
        }
        __syncthreads();
        if (pv && qs == 0) {
            int rank = cnt64[pl];        // keys unique -> exact rank
            astore64(&sKey[rank], lkey[p]);
            astore64(&sBox[rank], lbox[p]);
        }
        __syncthreads();   // drain scatter
        if (tid == 0) astorei(&arrw[bid * 32], ARR_TAG | 2);
        // ---- poll: all 16 blocks at phase >= 2 ----
        if (wv == 0) {
            bool need = lane < 16;
            for (;;) {
                int v = 0;
                if (need) v = aloadi(&arrw[lane * 32]);
                bool ok = !need || (((v & 0xFFFF0000) == ARR_TAG) && ((v & 0xFFFF) >= 2));
                if (__ballot(!ok) == 0) break;
                __builtin_amdgcn_s_sleep(1);
            }
        }
        __syncthreads();

        // ---- mask phase: sorted boxes -> LDS (reuse lkey region) ----
        u64* sb = lkey;
        for (int t = tid; t < n; t += 1024) sb[t] = aload64(&sBox[t]);
        __syncthreads();
        u64 myBoxS = 0;
        if (bid == 0 && tid < n) myBoxS = sb[tid];   // snapshot before tri overlay
        {
            int nq = (n + 3) >> 2;
            for (int rq = bid * 16 + wv; rq < nq; rq += NB * 16) {
                int r0 = rq << 2;
                int a = r0 >> 6;
                int rowBase = 64 * (a * W - (a * (a - 1)) / 2);
                int Wa = W - a;
                int rr1 = min(r0+1, n-1), rr2 = min(r0+2, n-1), rr3 = min(r0+3, n-1);
                u64 rp0 = sb[r0], rp1 = sb[rr1], rp2 = sb[rr2], rp3 = sb[rr3];
                int t1,t2,t3,t4;
                unpackBox(rp0,t1,t2,t3,t4); int ra0 = __mul24(t3-t1, t4-t2);
                unpackBox(rp1,t1,t2,t3,t4); int ra1 = __mul24(t3-t1, t4-t2);
                unpackBox(rp2,t1,t2,t3,t4); int ra2 = __mul24(t3-t1, t4-t2);
                unpackBox(rp3,t1,t2,t3,t4); int ra3 = __mul24(t3-t1, t4-t2);
                for (int k = 0; k < Wa; ++k) {
                    int wcol = a + k;
                    int c = (wcol << 6) + lane;
                    bool cv = c < n;
                    u64 cb = sb[cv ? c : (n - 1)];
                    int cx1, cy1, cx2, cy2; unpackBox(cb, cx1, cy1, cx2, cy2);
                    int car = __mul24(cx2 - cx1, cy2 - cy1);
                    u64 wb0 = iouBit(rp0, ra0, cx1, cy1, cx2, cy2, car, cv);
                    u64 wb1 = iouBit(rp1, ra1, cx1, cy1, cx2, cy2, car, cv);
                    u64 wb2 = iouBit(rp2, ra2, cx1, cy1, cx2, cy2, car, cv);
                    u64 wb3 = iouBit(rp3, ra3, cx1, cy1, cx2, cy2, car, cv);
                    if (lane < 4) {
                        int r = r0 + lane;
                        if (r < n) {
                            u64 word = (lane == 0) ? wb0 : (lane == 1) ? wb1
                                     : (lane == 2) ? wb2 : wb3;
                            int b = r & 63;
                            if (wcol == a) {   // diagonal word: clear cols <= r
                                u64 low = (b == 63) ? ~0ULL : ((1ULL << (b + 1)) - 1);
                                word &= ~low;
                            }
                            astore64(&triG[rowBase + b * Wa + k], word);
                        }
                    }
                }
            }
        }
        __syncthreads();   // drain tri stores

        if (bid != 0) {
            if (tid == 0) astorei(&arrw[bid * 32], ARR_TAG | 3);
            return;
        }
        // ---- block 0: poll blocks 1..15 at phase >= 3, tri -> LDS, scan, write ----
        if (wv == 0) {
            bool need = (lane >= 1) && (lane < 16);
            for (;;) {
                int v = 0;
                if (need) v = aloadi(&arrw[lane * 32]);
                bool ok = !need || (((v & 0xFFFF0000) == ARR_TAG) && ((v & 0xFFFF) >= 3));
                if (__ballot(!ok) == 0) break;
                __builtin_amdgcn_s_sleep(1);
            }
        }
        __syncthreads();
        {
            int A = n >> 6, B = n & 63;
            int total = 64 * (A * W - (A * (A - 1)) / 2) + B * (W - A);
            for (int t = tid; t < total; t += 1024) tri[t] = aload64(&triG[t]);
        }
        if (tid < 16) keptW[tid] = 0;
        __syncthreads();

        // ---- scan: lane-parallel lexicographic-MIS peeling per 64-word ----
        // (no per-kept serial chain; greedy == peeling: each round keeps rows
        //  with no lower ALIVE suppressor -- mins are mutually compatible)
        if (tid < 64 && n > 0) {
            const u64 lowMask = (1ULL << lane) - 1ULL;   // bits strictly below lane
            for (int cw2 = 0; cw2 < W; ++cw2) {
                // external suppression from kept rows of earlier words
                unsigned sLo = 0, sHi = 0;
                for (int wp = 0; wp < cw2; ++wp) {
                    u64 kwv = keptW[wp];          // uniform addr -> broadcast
                    if ((kwv >> lane) & 1ULL) {   // this lane's row was kept
                        int off = 64 * (wp * W - (wp * (wp - 1)) / 2)
                                + lane * (W - wp) + (cw2 - wp);
                        u64 v = tri[off];
                        sLo |= (unsigned)v; sHi |= (unsigned)(v >> 32);
                    }
                }
                #pragma unroll
                for (int m2 = 32; m2 >= 1; m2 >>= 1) {
                    sLo |= (unsigned)__shfl_xor((int)sLo, m2);
                    sHi |= (unsigned)__shfl_xor((int)sHi, m2);
                }
                int cnt2 = n - (cw2 << 6);
                u64 wmask = (cnt2 >= 64) ? ~0ULL
                          : ((cnt2 > 0) ? ((1ULL << cnt2) - 1) : 0ULL);
                u64 alive = wmask & ~(((u64)sHi << 32) | sLo);
                if (!alive) continue;             // uniform -> keptW stays 0

                // load this word's diag block rows (lane r holds row 64*cw2+r)
                int Wa = W - cw2;
                int base = 64 * (cw2 * W - (cw2 * (cw2 - 1)) / 2);
                u64 roww = 0;
                {
                    int r = (cw2 << 6) + lane;
                    if (r < n) roww = tri[base + lane * Wa];
                }
                // in-wave 64x64 bit-matrix transpose: lane j -> column j
                u64 tw = roww;
                {
                    const u64 mk0 = 0x00000000FFFFFFFFULL, mk1 = 0x0000FFFF0000FFFFULL,
                              mk2 = 0x00FF00FF00FF00FFULL, mk3 = 0x0F0F0F0F0F0F0F0FULL,
                              mk4 = 0x3333333333333333ULL, mk5 = 0x5555555555555555ULL;
                    u64 t2; int jj;
                    jj = 32; t2 = shflxor64(tw, jj);
                    tw = ((lane & jj) == 0) ? ((tw & mk0) | ((t2 & mk0) << jj))
                                            : (((t2 >> jj) & mk0) | (tw & ~mk0));
                    jj = 16; t2 = shflxor64(tw, jj);
                    tw = ((lane & jj) == 0) ? ((tw & mk1) | ((t2 & mk1) << jj))
                                            : (((t2 >> jj) & mk1) | (tw & ~mk1));
                    jj = 8;  t2 = shflxor64(tw, jj);
                    tw = ((lane & jj) == 0) ? ((tw & mk2) | ((t2 & mk2) << jj))
                                            : (((t2 >> jj) & mk2) | (tw & ~mk2));
                    jj = 4;  t2 = shflxor64(tw, jj);
                    tw = ((lane & jj) == 0) ? ((tw & mk3) | ((t2 & mk3) << jj))
                                            : (((t2 >> jj) & mk3) | (tw & ~mk3));
                    jj = 2;  t2 = shflxor64(tw, jj);
                    tw = ((lane & jj) == 0) ? ((tw & mk4) | ((t2 & mk4) << jj))
                                            : (((t2 >> jj) & mk4) | (tw & ~mk4));
                    jj = 1;  t2 = shflxor64(tw, jj);
                    tw = ((lane & jj) == 0) ? ((tw & mk5) | ((t2 & mk5) << jj))
                                            : (((t2 >> jj) & mk5) | (tw & ~mk5));
                }
                const u64 supCol = tw;   // bit i (lane j) = row i suppresses col j

                // peeling fixpoint (== greedy kept set for this word)
                u64 kept = 0;
                while (alive) {
                    bool aliveMe = (alive >> lane) & 1ULL;
                    u64 mins = __ballot(aliveMe && (supCol & alive & lowMask) == 0ULL);
                    kept |= mins;
                    u64 deadB = __ballot((supCol & mins) != 0ULL);
                    alive &= ~(mins | deadB);
                }
                if (lane == 0) keptW[cw2] = kept;
            }
        }
        __syncthreads();

        if (tid < n && ((keptW[tid >> 6] >> (tid & 63)) & 1ULL)) {
            u64 key = aload64(&sKey[tid]);
            unsigned u = ~(unsigned)(key >> 32);
            float score = __uint_as_float(u ^ 0x80000000u);
            int x1, y1, x2, y2; unpackBox(myBoxS, x1, y1, x2, y2);
            out[5*tid+0] = score;
            out[5*tid+1] = (float)x1;
            out[5*tid+2] = (float)y1;
            out[5*tid+3] = (float)(x2 - x1);
            out[5*tid+4] = (float)(y2 - y1);
        }
    } else {
        // ===== correctness-only fallback (n > NFAST; never expected) =====
        int zb = (5 * n + 31) & ~31; if (zb > 5 * NBOX) zb = 5 * NBOX;
        if (bid != 0) {   // zero tail share and exit; block 0 is self-sufficient
            for (int t = zb + ((bid - 1) << 10) + tid; t < 5 * NBOX; t += 15 * 1024)
                out[t] = 0.f;
            return;
        }
        for (int t = tid; t < zb; t += 1024) out[t] = 0.f;
        if (tid == 0) sCnt = 0;
        __syncthreads();
        #pragma unroll
        for (int kk = 0; kk < 8; ++kk) {
            int g = (kk << 10) + tid;
            if (g < NBOX) {
                const float* src; int local, i, j; float xps, yps; int pp;
                if (g < 1600) { src = outs0; local = g;        i = local/40; j = local - i*40; xps=16.f; yps=12.f; pp=1600; }
                else          { src = outs1; local = g - 1600; i = local/80; j = local - i*80; xps= 8.f; yps= 6.f; pp=6400; }
                float prob = src[local];
                if (prob > 0.9f) {
                    float b1 = src[pp + local], b2 = src[2*pp + local];
                    float b3 = src[3*pp + local], b4 = src[4*pp + local];
                    float c1 = b1*xps + (float)i*xps;
                    float c2 = b2*yps + (float)j*yps;
                    float X1 = rintf(c1), Y1 = rintf(c2);
                    float X2 = rintf(b3*640.0f + c1), Y2 = rintf(b4*480.0f + c2);
                    unsigned u = __float_as_uint(prob);
                    u ^= (u & 0x80000000u) ? 0xFFFFFFFFu : 0x80000000u;
                    u64 key = ((u64)(~u) << 32) | (unsigned)g;
                    int pos = atomicAdd(&sCnt, 1);
                    if (pos < 8192) {
                        fbKey[pos]  = key;
                        fbBoxC[pos] = packBox((int)X1, (int)Y1, (int)X2, (int)Y2);
                    }
                }
            }
        }
        __syncthreads();
        for (int p = tid; p < n; p += 1024) {
            u64 kp = fbKey[p];
            int rank = 0;
            for (int q = 0; q < n; ++q) rank += (fbKey[q] < kp) ? 1 : 0;
            sKey2[rank] = kp;
            sBox2[rank] = fbBoxC[p];
        }
        __syncthreads();
        if (tid < 64) {
            int kc = 0;
            for (int base2 = 0; base2 < n; base2 += 64) {
                int p = base2 + lane;
                bool in = p < n;
                u64 bp = in ? sBox2[p] : 0, kp2 = in ? sKey2[p] : 0;
                int x1, y1, x2, y2; unpackBox(bp, x1, y1, x2, y2);
                int ar = __mul24(x2 - x1, y2 - y1);
                bool dead = !in;
                for (int k = 0; k < kc; ++k) {
                    int kx1, ky1, kx2, ky2; unpackBox(kArr[k], kx1, ky1, kx2, ky2);
                    int kar = __mul24(kx2 - kx1, ky2 - ky1);
                    int iw = max(min(x2, kx2) - max(x1, kx1), 0);
                    int ih = max(min(y2, ky2) - max(y1, ky1), 0);
                    int I = __mul24(iw, ih); int P = ar + kar;
                    if (I < P && 3 * I > P) dead = true;
                }
                u64 scan = __ballot(!dead);
                while (scan) {
                    int t = (int)__builtin_ctzll(scan);
                    scan &= scan - 1;
                    u64 tb = __shfl(bp, t);
                    if (lane == t) {
                        kArr[kc] = bp;
                        unsigned u = ~(unsigned)(kp2 >> 32);
                        float score = __uint_as_float(u ^ 0x80000000u);
                        out[5*p+0] = score;
                        out[5*p+1] = (float)x1; out[5*p+2] = (float)y1;
                        out[5*p+3] = (float)(x2 - x1); out[5*p+4] = (float)(y2 - y1);
                    }
                    kc++;
                    bool kill = false;
                    if (!dead && lane > t) {
                        int tx1, ty1, tx2, ty2; unpackBox(tb, tx1, ty1, tx2, ty2);
                        int tar = __mul24(tx2 - tx1, ty2 - ty1);
                        int iw = max(min(x2, tx2) - max(x1, tx1), 0);
                        int ih = max(min(y2, ty2) - max(y1, ty1), 0);
                        int I = __mul24(iw, ih); int P = ar + tar;
                        kill = (I < P) && (3 * I > P);
                    }
                    dead = dead || kill;
                    scan &= ~__ballot(dead);
                }
            }
        }
    }
}

extern "C" void kernel_launch(void* const* d_in, const int* in_sizes, int n_in,
                              void* d_out, int out_size, void* d_ws, size_t ws_size,
                              hipStream_t stream) {
    const float* outs0 = (const float*)d_in[0];
    const float* outs1 = (const float*)d_in[1];
    float* out = (float*)d_out;
    char* ws = (char*)d_ws;
    size_t o = 0;
    int* ctrl   = (int*)(ws + o); o += 4096;               // 32 words x 128 B spacing
    u64* gKey   = (u64*)(ws + o); o += (size_t)8192 * 8;   // 64 KB (per-block segments)
    u64* gBox   = (u64*)(ws + o); o += (size_t)8192 * 8;   // 64 KB
    u64* sKey   = (u64*)(ws + o); o += (size_t)1024 * 8;   // 8 KB
    u64* sBox   = (u64*)(ws + o); o += (size_t)1024 * 8;   // 8 KB
    u64* triG   = (u64*)(ws + o); o += (size_t)6720 * 8;   // 52.5 KB
    u64* fbKey  = (u64*)(ws + o); o += (size_t)8192 * 8;   // 64 KB (fallback)
    u64* fbBoxC = (u64*)(ws + o); o += (size_t)8192 * 8;   // 64 KB (fallback)
    u64* sKey2  = (u64*)(ws + o); o += (size_t)8192 * 8;   // 64 KB (fallback)
    u64* sBox2  = (u64*)(ws + o); o += (size_t)8192 * 8;   // 64 KB (fallback)
    u64* kArr   = (u64*)(ws + o); o += (size_t)8192 * 8;   // 64 KB (fallback)

    hipLaunchKernelGGL(k_all, dim3(NB), dim3(1024), 0, stream,
                       outs0, outs1, out, ctrl, gKey, gBox, sKey, sBox, triG,
                       fbKey, fbBoxC, sKey2, sBox2, kArr);
}

// Round 18
// 92.184 us; speedup vs baseline: 1.4097x; 1.0759x over previous
//
#include <hip/hip_runtime.h>
#include <stdint.h>

#pragma clang fp contract(off)

#define NBOX 8000      // 5x40x40 + 5x80x80
#define NFAST 896      // fast path cap: W<=14, tri mask = 6720 u64 = 52.5 KB
#define NB 16          // grid blocks (<< 256 CUs -> co-resident)
typedef unsigned long long u64;

// Magic-tagged control words: ws is 0xAA-poisoned (or zeroed) before launch;
// (v & 0xFFFF0000) can never equal 0x7E30/0x7E32 from poison -> NO INIT NEEDED.
#define CNT_TAG 0x7E300000   // decode block b posts CNT_TAG | count
#define ARR_TAG 0x7E320000   // block b posts ARR_TAG | phase (2=rank done, 3=mask done)

__device__ __forceinline__ u64 aload64(u64* p) {
    return __hip_atomic_load(p, __ATOMIC_RELAXED, __HIP_MEMORY_SCOPE_AGENT);
}
__device__ __forceinline__ void astore64(u64* p, u64 v) {
    __hip_atomic_store(p, v, __ATOMIC_RELAXED, __HIP_MEMORY_SCOPE_AGENT);
}
__device__ __forceinline__ int aloadi(int* p) {
    return __hip_atomic_load(p, __ATOMIC_RELAXED, __HIP_MEMORY_SCOPE_AGENT);
}
__device__ __forceinline__ void astorei(int* p, int v) {
    __hip_atomic_store(p, v, __ATOMIC_RELAXED, __HIP_MEMORY_SCOPE_AGENT);
}

// pack 4 non-negative u16 coords: x1 | y1<<16 | x2<<32 | y2<<48
__device__ __forceinline__ u64 packBox(int x1, int y1, int x2, int y2) {
    return (u64)(unsigned)(x1 | (y1 << 16)) | ((u64)(unsigned)(x2 | (y2 << 16)) << 32);
}
__device__ __forceinline__ void unpackBox(u64 v, int& x1, int& y1, int& x2, int& y2) {
    unsigned lo = (unsigned)v, hi = (unsigned)(v >> 32);
    x1 = (int)(lo & 0xffffu); y1 = (int)(lo >> 16);
    x2 = (int)(hi & 0xffffu); y2 = (int)(hi >> 16);
}
__device__ __forceinline__ u64 iouBit(u64 rp, int ra, int cx1, int cy1, int cx2, int cy2,
                                      int car, bool cv) {
    int rx1, ry1, rx2, ry2; unpackBox(rp, rx1, ry1, rx2, ry2);
    int iw = max(min(rx2, cx2) - max(rx1, cx1), 0);
    int ih = max(min(ry2, cy2) - max(ry1, cy1), 0);
    int I = __mul24(iw, ih); int P = ra + car;          // exact: ints < 2^23
    return __ballot(cv && (I < P) && (3 * I > P));      // uni>0 && inter>0.5*uni
}

// ctrl (int*): cnt_b at ctrl[b*32] (b<8); arr_b at ctrl[(16+b)*32]. 128-B spacing.
__global__ __launch_bounds__(1024) void k_all(
    const float* __restrict__ outs0, const float* __restrict__ outs1,
    float* __restrict__ out,
    int* __restrict__ ctrl,
    u64* __restrict__ gKey, u64* __restrict__ gBox,      // [8192] per-block segments
    u64* __restrict__ sKey, u64* __restrict__ sBox,      // [1024] sorted
    u64* __restrict__ triG,                              // [6720] tri mask (upper)
    u64* __restrict__ triDG,                             // [896] diag low words (supCol)
    u64* __restrict__ fbKey, u64* __restrict__ fbBoxC,   // fallback scratch
    u64* __restrict__ sKey2, u64* __restrict__ sBox2, u64* __restrict__ kArr)
{
    __shared__ __attribute__((aligned(16))) char pool[53760];  // tri overlay (52.5 KB)
    u64* lkey = (u64*)pool;            // packed keys   [<=1024]
    u64* lbox = (u64*)(pool + 8192);   // packed boxes  [<=1024]
    u64* tri  = (u64*)pool;            // block 0 scan overlay
    __shared__ u64 triDs[896];         // supCol diag words (7 KB)
    __shared__ int cnt64[64];
    __shared__ int pre[8], cnts[8];
    __shared__ int sCnt, sN;
    __shared__ u64 keptW[16];
    const int tid = threadIdx.x, bid = blockIdx.x;
    const int wv = tid >> 6, lane = tid & 63;
    int* cntw = ctrl;
    int* arrw = ctrl + 16 * 32;

    if (tid == 0) sCnt = 0;
    __syncthreads();

    // ---- Phase A: decode blocks 0..7, one box/thread, publish to own segment ----
    bool valid = false; u64 myKey = 0, myPk = 0;
    if (bid < 8) {
        int g = (bid << 10) + tid;
        if (g < NBOX) {
            const float* src; int local, i, j; float xps, yps; int pp;
            if (g < 1600) { src = outs0; local = g;        i = local/40; j = local - i*40; xps=16.f; yps=12.f; pp=1600; }
            else          { src = outs1; local = g - 1600; i = local/80; j = local - i*80; xps= 8.f; yps= 6.f; pp=6400; }
            float prob = src[local];
            if (prob > 0.9f) {
                float b1 = src[pp + local], b2 = src[2*pp + local];
                float b3 = src[3*pp + local], b4 = src[4*pp + local];
                // reference: ROW idx i scales x (ii[:,None]); COL idx j scales y
                float c1 = b1*xps + (float)i*xps;
                float c2 = b2*yps + (float)j*yps;
                float X1 = rintf(c1), Y1 = rintf(c2);
                float X2 = rintf(b3*640.0f + c1), Y2 = rintf(b4*480.0f + c2);
                unsigned u = __float_as_uint(prob);
                u ^= (u & 0x80000000u) ? 0xFFFFFFFFu : 0x80000000u;  // monotone map
                myKey = ((u64)(~u) << 32) | (unsigned)g;  // asc = desc score, asc g
                myPk = packBox((int)X1, (int)Y1, (int)X2, (int)Y2);
                valid = true;
            }
        }
        u64 bal = __ballot(valid);
        int wcnt = (int)__popcll(bal);
        int wbase = 0;
        if (lane == 0 && wcnt) wbase = atomicAdd(&sCnt, wcnt);
        wbase = __shfl(wbase, 0);
        int posl = wbase + (int)__popcll(bal & ((1ULL << lane) - 1ULL));
        if (valid) {
            astore64(&gKey[(bid << 10) + posl], myKey);
            astore64(&gBox[(bid << 10) + posl], myPk);
        }
        __syncthreads();   // drain segment stores (vmcnt(0) at barrier)
        if (tid == 0) astorei(&cntw[bid * 32], CNT_TAG | sCnt);
    }

    // ---- all blocks: poll the 8 count markers, compute n + prefix locally ----
    if (wv == 0) {
        bool need = lane < 8;
        int v = 0;
        for (;;) {
            if (need) v = aloadi(&cntw[lane * 32]);
            bool ok = !need || ((v & 0xFFFF0000) == CNT_TAG);
            if (__ballot(!ok) == 0) break;
            __builtin_amdgcn_s_sleep(1);
        }
        if (need) {
            int c = v & 0xFFFF;
            int p2 = 0;
            #pragma unroll
            for (int i2 = 0; i2 < 8; ++i2) {
                int ci = __shfl(c, i2);
                if (i2 < lane) p2 += ci;
            }
            pre[lane] = p2;
            cnts[lane] = c;
            if (lane == 7) sN = p2 + c;
        }
    }
    __syncthreads();
    int n = sN; if (n > NBOX) n = NBOX;

    if (n <= NFAST) {
        const int W = (n + 63) >> 6;
        // ---- zero partition, 128-B aligned split ----
        int zb = (5 * n + 31) & ~31;
        if (bid == 0) {
            for (int t = tid; t < zb; t += 1024) out[t] = 0.f;
        } else {
            for (int t = zb + ((bid - 1) << 10) + tid; t < 5 * NBOX; t += 15 * 1024)
                out[t] = 0.f;
        }

        // ---- bulk-load 8 segments -> packed LDS ----
        #pragma unroll
        for (int b2 = 0; b2 < 8; ++b2) {
            int c = cnts[b2], p0 = pre[b2];
            for (int i2 = tid; i2 < c; i2 += 1024) {
                lkey[p0 + i2] = aload64(&gKey[(b2 << 10) + i2]);
                lbox[p0 + i2] = aload64(&gBox[(b2 << 10) + i2]);
            }
        }
        if (tid < 64) cnt64[tid] = 0;
        __syncthreads();

        // ---- rank-count own p-slice over packed LDS keys ----
        int pc = (n + 15) >> 4;
        int pl = tid >> 4, qs = tid & 15;
        int p = bid * pc + pl;
        bool pv = (pl < pc) && (p < n);
        if (pv) {
            u64 kp = lkey[p];
            int qlo = qs * pc, qhi = min(qlo + pc, n);
            int c2 = 0;
            for (int q = qlo; q < qhi; ++q) c2 += (lkey[q] < kp) ? 1 : 0;
            if (c2) atomicAdd(&cnt64[pl], c2);
        }
        __syncthreads();
        if (pv && qs == 0) {
            int rank = cnt64[pl];        // keys unique -> exact rank
            astore64(&sKey[rank], lkey[p]);
            astore64(&sBox[rank], lbox[p]);
        }
        __syncthreads();   // drain scatter
        if (tid == 0) astorei(&arrw[bid * 32], ARR_TAG | 2);
        // ---- poll: all 16 blocks at phase >= 2 ----
        if (wv == 0) {
            bool need = lane < 16;
            for (;;) {
                int v = 0;
                if (need) v = aloadi(&arrw[lane * 32]);
                bool ok = !need || (((v & 0xFFFF0000) == ARR_TAG) && ((v & 0xFFFF) >= 2));
                if (__ballot(!ok) == 0) break;
                __builtin_amdgcn_s_sleep(1);
            }
        }
        __syncthreads();

        // ---- mask phase: sorted boxes -> LDS (reuse lkey region) ----
        u64* sb = lkey;
        for (int t = tid; t < n; t += 1024) sb[t] = aload64(&sBox[t]);
        __syncthreads();
        u64 myBoxS = 0;
        if (bid == 0 && tid < n) myBoxS = sb[tid];   // snapshot before tri overlay
        {
            int nq = (n + 3) >> 2;
            for (int rq = bid * 16 + wv; rq < nq; rq += NB * 16) {
                int r0 = rq << 2;
                int a = r0 >> 6;
                int rowBase = 64 * (a * W - (a * (a - 1)) / 2);
                int Wa = W - a;
                int rr1 = min(r0+1, n-1), rr2 = min(r0+2, n-1), rr3 = min(r0+3, n-1);
                u64 rp0 = sb[r0], rp1 = sb[rr1], rp2 = sb[rr2], rp3 = sb[rr3];
                int t1,t2,t3,t4;
                unpackBox(rp0,t1,t2,t3,t4); int ra0 = __mul24(t3-t1, t4-t2);
                unpackBox(rp1,t1,t2,t3,t4); int ra1 = __mul24(t3-t1, t4-t2);
                unpackBox(rp2,t1,t2,t3,t4); int ra2 = __mul24(t3-t1, t4-t2);
                unpackBox(rp3,t1,t2,t3,t4); int ra3 = __mul24(t3-t1, t4-t2);
                for (int k = 0; k < Wa; ++k) {
                    int wcol = a + k;
                    int c = (wcol << 6) + lane;
                    bool cv = c < n;
                    u64 cb = sb[cv ? c : (n - 1)];
                    int cx1, cy1, cx2, cy2; unpackBox(cb, cx1, cy1, cx2, cy2);
                    int car = __mul24(cx2 - cx1, cy2 - cy1);
                    u64 wb0 = iouBit(rp0, ra0, cx1, cy1, cx2, cy2, car, cv);
                    u64 wb1 = iouBit(rp1, ra1, cx1, cy1, cx2, cy2, car, cv);
                    u64 wb2 = iouBit(rp2, ra2, cx1, cy1, cx2, cy2, car, cv);
                    u64 wb3 = iouBit(rp3, ra3, cx1, cy1, cx2, cy2, car, cv);
                    if (lane < 4) {
                        int r = r0 + lane;
                        if (r < n) {
                            u64 word = (lane == 0) ? wb0 : (lane == 1) ? wb1
                                     : (lane == 2) ? wb2 : wb3;
                            int b = r & 63;
                            if (wcol == a) {   // diagonal word
                                // supCol for col r = strictly-low bits of full row
                                // (suppression predicate is symmetric in (i,j))
                                astore64(&triDG[(wcol << 6) + b],
                                         word & ((1ULL << b) - 1));
                                u64 low = (b == 63) ? ~0ULL : ((1ULL << (b + 1)) - 1);
                                word &= ~low;  // clear cols <= r for upper tri
                            }
                            astore64(&triG[rowBase + b * Wa + k], word);
                        }
                    }
                }
            }
        }
        __syncthreads();   // drain tri stores

        if (bid != 0) {
            if (tid == 0) astorei(&arrw[bid * 32], ARR_TAG | 3);
            return;
        }
        // ---- block 0: poll blocks 1..15 at phase >= 3, tri -> LDS, scan, write ----
        if (wv == 0) {
            bool need = (lane >= 1) && (lane < 16);
            for (;;) {
                int v = 0;
                if (need) v = aloadi(&arrw[lane * 32]);
                bool ok = !need || (((v & 0xFFFF0000) == ARR_TAG) && ((v & 0xFFFF) >= 3));
                if (__ballot(!ok) == 0) break;
                __builtin_amdgcn_s_sleep(1);
            }
        }
        __syncthreads();
        {
            int A = n >> 6, B = n & 63;
            int total = 64 * (A * W - (A * (A - 1)) / 2) + B * (W - A);
            for (int t = tid; t < total; t += 1024) tri[t] = aload64(&triG[t]);
            for (int t = tid; t < (W << 6); t += 1024) triDs[t] = aload64(&triDG[t]);
        }
        if (tid < 16) keptW[tid] = 0;
        __syncthreads();

        // ---- scan: lane-parallel lexicographic-MIS peeling per 64-word ----
        // supCol read directly from triDs (no transpose); ext suppression via
        // per-lane keptMine register mask + fully-unrolled predicated loads.
        if (tid < 64 && n > 0) {
            const u64 lowMask = (1ULL << lane) - 1ULL;   // bits strictly below lane
            unsigned keptMine = 0;   // bit wp = my row (64*wp+lane) was kept
            for (int cw2 = 0; cw2 < W; ++cw2) {
                // external suppression: my kept rows' tri words for col-word cw2
                unsigned sLo = 0, sHi = 0;
                #pragma unroll
                for (int wp = 0; wp < 14; ++wp) {
                    if (wp < cw2 && ((keptMine >> wp) & 1u)) {
                        int off = 64 * (wp * W - (wp * (wp - 1)) / 2)
                                + lane * (W - wp) + (cw2 - wp);
                        u64 v = tri[off];
                        sLo |= (unsigned)v; sHi |= (unsigned)(v >> 32);
                    }
                }
                #pragma unroll
                for (int m2 = 32; m2 >= 1; m2 >>= 1) {
                    sLo |= (unsigned)__shfl_xor((int)sLo, m2);
                    sHi |= (unsigned)__shfl_xor((int)sHi, m2);
                }
                int cnt2 = n - (cw2 << 6);
                u64 wmask = (cnt2 >= 64) ? ~0ULL
                          : ((cnt2 > 0) ? ((1ULL << cnt2) - 1) : 0ULL);
                u64 alive = wmask & ~(((u64)sHi << 32) | sLo);
                if (!alive) continue;             // uniform -> keptW stays 0

                const u64 supCol = triDs[(cw2 << 6) + lane];  // rows < lane that suppress me

                // peeling fixpoint (== greedy kept set for this word)
                u64 kept = 0;
                while (alive) {
                    bool aliveMe = (alive >> lane) & 1ULL;
                    u64 mins = __ballot(aliveMe && (supCol & alive & lowMask) == 0ULL);
                    kept |= mins;
                    u64 deadB = __ballot((supCol & mins) != 0ULL);
                    alive &= ~(mins | deadB);
                }
                if (lane == 0) keptW[cw2] = kept;
                keptMine |= (unsigned)((kept >> lane) & 1ULL) << cw2;
            }
        }
        __syncthreads();

        if (tid < n && ((keptW[tid >> 6] >> (tid & 63)) & 1ULL)) {
            u64 key = aload64(&sKey[tid]);
            unsigned u = ~(unsigned)(key >> 32);
            float score = __uint_as_float(u ^ 0x80000000u);
            int x1, y1, x2, y2; unpackBox(myBoxS, x1, y1, x2, y2);
            out[5*tid+0] = score;
            out[5*tid+1] = (float)x1;
            out[5*tid+2] = (float)y1;
            out[5*tid+3] = (float)(x2 - x1);
            out[5*tid+4] = (float)(y2 - y1);
        }
    } else {
        // ===== correctness-only fallback (n > NFAST; never expected) =====
        int zb = (5 * n + 31) & ~31; if (zb > 5 * NBOX) zb = 5 * NBOX;
        if (bid != 0) {   // zero tail share and exit; block 0 is self-sufficient
            for (int t = zb + ((bid - 1) << 10) + tid; t < 5 * NBOX; t += 15 * 1024)
                out[t] = 0.f;
            return;
        }
        for (int t = tid; t < zb; t += 1024) out[t] = 0.f;
        if (tid == 0) sCnt = 0;
        __syncthreads();
        #pragma unroll
        for (int kk = 0; kk < 8; ++kk) {
            int g = (kk << 10) + tid;
            if (g < NBOX) {
                const float* src; int local, i, j; float xps, yps; int pp;
                if (g < 1600) { src = outs0; local = g;        i = local/40; j = local - i*40; xps=16.f; yps=12.f; pp=1600; }
                else          { src = outs1; local = g - 1600; i = local/80; j = local - i*80; xps= 8.f; yps= 6.f; pp=6400; }
                float prob = src[local];
                if (prob > 0.9f) {
                    float b1 = src[pp + local], b2 = src[2*pp + local];
                    float b3 = src[3*pp + local], b4 = src[4*pp + local];
                    float c1 = b1*xps + (float)i*xps;
                    float c2 = b2*yps + (float)j*yps;
                    float X1 = rintf(c1), Y1 = rintf(c2);
                    float X2 = rintf(b3*640.0f + c1), Y2 = rintf(b4*480.0f + c2);
                    unsigned u = __float_as_uint(prob);
                    u ^= (u & 0x80000000u) ? 0xFFFFFFFFu : 0x80000000u;
                    u64 key = ((u64)(~u) << 32) | (unsigned)g;
                    int pos = atomicAdd(&sCnt, 1);
                    if (pos < 8192) {
                        fbKey[pos]  = key;
                        fbBoxC[pos] = packBox((int)X1, (int)Y1, (int)X2, (int)Y2);
                    }
                }
            }
        }
        __syncthreads();
        for (int p = tid; p < n; p += 1024) {
            u64 kp = fbKey[p];
            int rank = 0;
            for (int q = 0; q < n; ++q) rank += (fbKey[q] < kp) ? 1 : 0;
            sKey2[rank] = kp;
            sBox2[rank] = fbBoxC[p];
        }
        __syncthreads();
        if (tid < 64) {
            int kc = 0;
            for (int base2 = 0; base2 < n; base2 += 64) {
                int p = base2 + lane;
                bool in = p < n;
                u64 bp = in ? sBox2[p] : 0, kp2 = in ? sKey2[p] : 0;
                int x1, y1, x2, y2; unpackBox(bp, x1, y1, x2, y2);
                int ar = __mul24(x2 - x1, y2 - y1);
                bool dead = !in;
                for (int k = 0; k < kc; ++k) {
                    int kx1, ky1, kx2, ky2; unpackBox(kArr[k], kx1, ky1, kx2, ky2);
                    int kar = __mul24(kx2 - kx1, ky2 - ky1);
                    int iw = max(min(x2, kx2) - max(x1, kx1), 0);
                    int ih = max(min(y2, ky2) - max(y1, ky1), 0);
                    int I = __mul24(iw, ih); int P = ar + kar;
                    if (I < P && 3 * I > P) dead = true;
                }
                u64 scan = __ballot(!dead);
                while (scan) {
                    int t = (int)__builtin_ctzll(scan);
                    scan &= scan - 1;
                    u64 tb = __shfl(bp, t);
                    if (lane == t) {
                        kArr[kc] = bp;
                        unsigned u = ~(unsigned)(kp2 >> 32);
                        float score = __uint_as_float(u ^ 0x80000000u);
                        out[5*p+0] = score;
                        out[5*p+1] = (float)x1; out[5*p+2] = (float)y1;
                        out[5*p+3] = (float)(x2 - x1); out[5*p+4] = (float)(y2 - y1);
                    }
                    kc++;
                    bool kill = false;
                    if (!dead && lane > t) {
                        int tx1, ty1, tx2, ty2; unpackBox(tb, tx1, ty1, tx2, ty2);
                        int tar = __mul24(tx2 - tx1, ty2 - ty1);
                        int iw = max(min(x2, tx2) - max(x1, tx1), 0);
                        int ih = max(min(y2, ty2) - max(y1, ty1), 0);
                        int I = __mul24(iw, ih); int P = ar + tar;
                        kill = (I < P) && (3 * I > P);
                    }
                    dead = dead || kill;
                    scan &= ~__ballot(dead);
                }
            }
        }
    }
}

extern "C" void kernel_launch(void* const* d_in, const int* in_sizes, int n_in,
                              void* d_out, int out_size, void* d_ws, size_t ws_size,
                              hipStream_t stream) {
    const float* outs0 = (const float*)d_in[0];
    const float* outs1 = (const float*)d_in[1];
    float* out = (float*)d_out;
    char* ws = (char*)d_ws;
    size_t o = 0;
    int* ctrl   = (int*)(ws + o); o += 4096;               // 32 words x 128 B spacing
    u64* gKey   = (u64*)(ws + o); o += (size_t)8192 * 8;   // 64 KB (per-block segments)
    u64* gBox   = (u64*)(ws + o); o += (size_t)8192 * 8;   // 64 KB
    u64* sKey   = (u64*)(ws + o); o += (size_t)1024 * 8;   // 8 KB
    u64* sBox   = (u64*)(ws + o); o += (size_t)1024 * 8;   // 8 KB
    u64* triG   = (u64*)(ws + o); o += (size_t)6720 * 8;   // 52.5 KB
    u64* triDG  = (u64*)(ws + o); o += (size_t)896 * 8;    // 7 KB (diag supCol)
    u64* fbKey  = (u64*)(ws + o); o += (size_t)8192 * 8;   // 64 KB (fallback)
    u64* fbBoxC = (u64*)(ws + o); o += (size_t)8192 * 8;   // 64 KB (fallback)
    u64* sKey2  = (u64*)(ws + o); o += (size_t)8192 * 8;   // 64 KB (fallback)
    u64* sBox2  = (u64*)(ws + o); o += (size_t)8192 * 8;   // 64 KB (fallback)
    u64* kArr   = (u64*)(ws + o); o += (size_t)8192 * 8;   // 64 KB (fallback)

    hipLaunchKernelGGL(k_all, dim3(NB), dim3(1024), 0, stream,
                       outs0, outs1, out, ctrl, gKey, gBox, sKey, sBox, triG, triDG,
                       fbKey, fbBoxC, sKey2, sBox2, kArr);
}